// Round 1
// baseline (1229.182 us; speedup 1.0000x reference)
//
#include <hip/hip_runtime.h>

#define NMETA 64
#define MSUB 1024
#define NNODES 65536          // NMETA*MSUB
#define D 128
#define DOUT 64
#define NEDGES 1048576
#define COLS 131072           // MSUB*D, columns of the meta-mix view

// ---------------------------------------------------------------- CSR build
__global__ void k_zero_cnt(int* __restrict__ cnt) {
    cnt[blockIdx.x * 256 + threadIdx.x] = 0;
}

__global__ void k_hist(const int* __restrict__ dst, int* __restrict__ cnt) {
    int e = blockIdx.x * 256 + threadIdx.x;
    atomicAdd(&cnt[dst[e]], 1);
}

// single block, 1024 threads: exclusive scan of 65536 counts -> offsets,
// also fills the fill-cursor copy and dinv = rsqrt(deg) with deg = cnt + 1 (self loop)
__global__ __launch_bounds__(1024) void k_scan(const int* __restrict__ cnt,
                                               int* __restrict__ offs,
                                               int* __restrict__ nxt,
                                               float* __restrict__ dinv) {
    __shared__ int sh[1024];
    int t = threadIdx.x;
    int base = t * 64;
    int s = 0;
    for (int k = 0; k < 64; ++k) s += cnt[base + k];
    sh[t] = s;
    __syncthreads();
    for (int d = 1; d < 1024; d <<= 1) {
        int v = (t >= d) ? sh[t - d] : 0;
        __syncthreads();
        sh[t] += v;
        __syncthreads();
    }
    int run = (t == 0) ? 0 : sh[t - 1];
    for (int k = 0; k < 64; ++k) {
        int c = cnt[base + k];
        offs[base + k] = run;
        nxt[base + k]  = run;
        dinv[base + k] = rsqrtf((float)(c + 1));
        run += c;
    }
    if (t == 1023) offs[65536] = run;
}

__global__ void k_fill(const int* __restrict__ src, const int* __restrict__ dst,
                       int* __restrict__ nxt, int* __restrict__ csr) {
    int e = blockIdx.x * 256 + threadIdx.x;
    int d = dst[e];
    int p = atomicAdd(&nxt[d], 1);
    csr[p] = src[e];
}

// ---------------------------------------------------------- adjacency powers
// writes AT[i][j][n] = (A^(i+1))[n][j]  (transposed, so mix reads contiguous n)
__global__ __launch_bounds__(256) void k_adjpow(const float* __restrict__ A,
                                                float* __restrict__ AT) {
    __shared__ float As[4096];
    __shared__ float Bs[4096];
    int t = threadIdx.x;
    for (int q = 0; q < 16; ++q) As[t + 256 * q] = A[t + 256 * q];
    __syncthreads();
    for (int q = 0; q < 16; ++q) {
        int idx = t + 256 * q;
        int n = idx >> 6, j = idx & 63;
        AT[j * 64 + n] = As[idx];
        float acc = 0.f;
        for (int k = 0; k < 64; ++k) acc += As[n * 64 + k] * As[k * 64 + j];
        Bs[idx] = acc;
        AT[4096 + j * 64 + n] = acc;
    }
    __syncthreads();
    for (int q = 0; q < 16; ++q) {
        int idx = t + 256 * q;
        int n = idx >> 6, j = idx & 63;
        float acc = 0.f;
        for (int k = 0; k < 64; ++k) acc += Bs[n * 64 + k] * As[k * 64 + j];
        AT[8192 + j * 64 + n] = acc;
    }
}

// ------------------------------------------------------------------- GEMM
// C[64 x BN] per block = X[64 x 128] @ W[128 x BN]; fp32 LDS-tiled.
// blockIdx.z selects a W/C pair via strides (used for the 4 per-layer convs).
template <int BN, bool BIAS, bool RELU>
__global__ __launch_bounds__(256) void k_gemm(const float* __restrict__ X,
                                              const float* __restrict__ W,
                                              const float* __restrict__ bias,
                                              float* __restrict__ C,
                                              long wz, long cz) {
    const float* Wz = W + wz * blockIdx.z;
    float* Cz = C + cz * blockIdx.z;
    int row0 = blockIdx.x * 64;
    __shared__ float Xs[64][33];            // [row][k], padded: broadcast b32 reads
    __shared__ __align__(16) float Ws[32][BN];
    int t = threadIdx.x;
    constexpr int CG = BN / 4;              // col groups of 4
    constexpr int RPT = 64 / (256 / CG);    // rows per thread
    int cm = t % CG;
    int rm = t / CG;
    float acc[RPT][4];
#pragma unroll
    for (int r = 0; r < RPT; ++r)
#pragma unroll
        for (int c = 0; c < 4; ++c) acc[r][c] = 0.f;

    for (int kb = 0; kb < 128; kb += 32) {
#pragma unroll
        for (int q = 0; q < 2; ++q) {       // X tile: 512 float4
            int id = t * 2 + q;
            int r = id >> 3;
            int kk = (id & 7) * 4;
            float4 v = *(const float4*)(X + (long)(row0 + r) * 128 + kb + kk);
            Xs[r][kk + 0] = v.x; Xs[r][kk + 1] = v.y;
            Xs[r][kk + 2] = v.z; Xs[r][kk + 3] = v.w;
        }
        constexpr int WF4 = 32 * BN / 4;
#pragma unroll
        for (int q = 0; q < WF4 / 256; ++q) {  // W tile
            int id = t + 256 * q;
            int kk = id / (BN / 4);
            int ff = (id % (BN / 4)) * 4;
            *(float4*)&Ws[kk][ff] = *(const float4*)(Wz + (long)(kb + kk) * BN + ff);
        }
        __syncthreads();
#pragma unroll
        for (int k = 0; k < 32; ++k) {
            float4 w4 = *(const float4*)&Ws[k][cm * 4];
            float xr[RPT];
#pragma unroll
            for (int r = 0; r < RPT; ++r) xr[r] = Xs[rm * RPT + r][k];
#pragma unroll
            for (int r = 0; r < RPT; ++r) {
                acc[r][0] += xr[r] * w4.x;
                acc[r][1] += xr[r] * w4.y;
                acc[r][2] += xr[r] * w4.z;
                acc[r][3] += xr[r] * w4.w;
            }
        }
        __syncthreads();
    }
#pragma unroll
    for (int r = 0; r < RPT; ++r) {
        int row = row0 + rm * RPT + r;
        float4 v = make_float4(acc[r][0], acc[r][1], acc[r][2], acc[r][3]);
        if (BIAS) {
            v.x += bias[cm * 4 + 0]; v.y += bias[cm * 4 + 1];
            v.z += bias[cm * 4 + 2]; v.w += bias[cm * 4 + 3];
        }
        if (RELU) {
            v.x = fmaxf(v.x, 0.f); v.y = fmaxf(v.y, 0.f);
            v.z = fmaxf(v.z, 0.f); v.w = fmaxf(v.w, 0.f);
        }
        *(float4*)(Cz + (long)row * BN + cm * 4) = v;
    }
}

// ---------------------------------------------------------------- meta mix
// Y[n, c] = U0[n, c] + sum_{i=1..3} sum_j A_i[n, j] * U_i[j, c]
// block: 256 cols; acc[64] (one per meta node) lives in VGPRs; U_i tiles staged
// in LDS; AT reads are wave-uniform -> s_load.
__global__ __launch_bounds__(256) void k_mix(const float* __restrict__ U,
                                             const float* __restrict__ AT,
                                             float* __restrict__ Y) {
    __shared__ float Us[64 * 256];
    int t = threadIdx.x;
    long c0 = (long)blockIdx.x * 256;
    float acc[64];
#pragma unroll
    for (int n = 0; n < 64; ++n) acc[n] = 0.f;

    for (int i = 0; i < 3; ++i) {
        const float* Ui = U + (long)(i + 1) * NNODES * D;
        __syncthreads();
        for (int j = 0; j < 64; ++j) Us[j * 256 + t] = Ui[(long)j * COLS + c0 + t];
        __syncthreads();
        const float* ATi = AT + i * 4096;
        for (int j = 0; j < 64; ++j) {
            float l = Us[j * 256 + t];
#pragma unroll
            for (int n = 0; n < 64; ++n) acc[n] += ATi[j * 64 + n] * l;
        }
    }
    for (int n = 0; n < 64; ++n)
        Y[(long)n * COLS + c0 + t] = U[(long)n * COLS + c0 + t] + acc[n];
}

// -------------------------------------------------------------- propagation
// one wave per node; Xout[v] = relu(dinv[v]*sum_{u->v} dinv[u]*Y[u]
//                                  + dinv[v]^2*Y[v] + sum_i b[i])
__global__ __launch_bounds__(256) void k_prop(const float* __restrict__ Y,
                                              const int* __restrict__ offs,
                                              const int* __restrict__ csr,
                                              const float* __restrict__ dinv,
                                              const float* __restrict__ bias4,
                                              float* __restrict__ Xout) {
    int v = (blockIdx.x * 256 + threadIdx.x) >> 6;   // wave-uniform
    int lane = threadIdx.x & 63;
    const float2* Y2 = (const float2*)Y;
    float dv = dinv[v];
    float2 self = Y2[(long)v * 64 + lane];
    int e0 = offs[v], e1 = offs[v + 1];
    float ax = 0.f, ay = 0.f;
    for (int e = e0; e < e1; ++e) {
        int u = csr[e];                               // uniform -> s_load
        float du = dinv[u];
        float2 yv = Y2[(long)u * 64 + lane];
        ax += du * yv.x;
        ay += du * yv.y;
    }
    int f = lane * 2;
    float b0 = bias4[f] + bias4[128 + f] + bias4[256 + f] + bias4[384 + f];
    float b1 = bias4[f + 1] + bias4[129 + f] + bias4[257 + f] + bias4[385 + f];
    float ox = fmaxf(dv * ax + dv * dv * self.x + b0, 0.f);
    float oy = fmaxf(dv * ay + dv * dv * self.y + b1, 0.f);
    ((float2*)Xout)[(long)v * 64 + lane] = make_float2(ox, oy);
}

// ------------------------------------------------------------------ launch
extern "C" void kernel_launch(void* const* d_in, const int* in_sizes, int n_in,
                              void* d_out, int out_size, void* d_ws, size_t ws_size,
                              hipStream_t stream) {
    const float* x      = (const float*)d_in[0];
    const int*   subadj = (const int*)d_in[1];
    const float* adj    = (const float*)d_in[2];
    const float* gcn_W  = (const float*)d_in[3];
    const float* gcn_b  = (const float*)d_in[4];
    const float* lin_W1 = (const float*)d_in[5];
    const float* lin_b1 = (const float*)d_in[6];
    const float* lin_W2 = (const float*)d_in[7];
    const float* lin_b2 = (const float*)d_in[8];
    float* out = (float*)d_out;

    const int* e_src = subadj;
    const int* e_dst = subadj + NEDGES;

    char* w = (char*)d_ws;
    int*   cnt  = (int*)w;        w += (size_t)65536 * 4;
    int*   offs = (int*)w;        w += (size_t)65540 * 4;     // 65537, padded
    int*   nxt  = (int*)w;        w += (size_t)65536 * 4;
    int*   csr  = (int*)w;        w += (size_t)NEDGES * 4;
    float* dinv = (float*)w;      w += (size_t)65536 * 4;
    float* AT   = (float*)w;      w += (size_t)3 * 4096 * 4;
    float* bufX = (float*)w;      w += (size_t)NNODES * D * 4;
    float* bufU = (float*)w;      w += (size_t)4 * NNODES * D * 4;
    float* bufY = (float*)w;      w += (size_t)NNODES * D * 4;

    // CSR + degrees
    k_zero_cnt<<<256, 256, 0, stream>>>(cnt);
    k_hist<<<NEDGES / 256, 256, 0, stream>>>(e_dst, cnt);
    k_scan<<<1, 1024, 0, stream>>>(cnt, offs, nxt, dinv);
    k_fill<<<NEDGES / 256, 256, 0, stream>>>(e_src, e_dst, nxt, csr);
    k_adjpow<<<1, 256, 0, stream>>>(adj, AT);

    const float* Xcur = x;
    for (int li = 0; li < 3; ++li) {
        k_gemm<128, false, false><<<dim3(NNODES / 64, 1, 4), 256, 0, stream>>>(
            Xcur, gcn_W + (size_t)li * 4 * 16384, nullptr, bufU,
            16384L, (long)NNODES * D);
        k_mix<<<COLS / 256, 256, 0, stream>>>(bufU, AT, bufY);
        k_prop<<<NNODES / 4, 256, 0, stream>>>(bufY, offs, csr, dinv,
                                               gcn_b + (size_t)li * 512, bufX);
        Xcur = bufX;
    }
    k_gemm<128, true, true><<<NNODES / 64, 256, 0, stream>>>(
        bufX, lin_W1, lin_b1, bufY, 0L, 0L);
    k_gemm<64, true, false><<<NNODES / 64, 256, 0, stream>>>(
        bufY, lin_W2, lin_b2, out, 0L, 0L);
}

// Round 2
// 976.124 us; speedup vs baseline: 1.2592x; 1.2592x over previous
//
#include <hip/hip_runtime.h>

#define NMETA 64
#define MSUB 1024
#define NNODES 65536          // NMETA*MSUB
#define D 128
#define DOUT 64
#define NEDGES 1048576
#define COLS 131072           // MSUB*D

typedef __attribute__((ext_vector_type(8))) short bf8_t;   // 8 bf16 = 4 VGPRs
typedef __attribute__((ext_vector_type(4))) float f4_t;

__device__ inline unsigned short bfr(float x) {            // fp32 -> bf16 RNE
    unsigned u = __builtin_bit_cast(unsigned, x);
    u += 0x7fffu + ((u >> 16) & 1u);
    return (unsigned short)(u >> 16);
}

// ---------------------------------------------------------------- CSR build
__global__ void k_zero_cnt(int* __restrict__ cnt) {
    cnt[blockIdx.x * 256 + threadIdx.x] = 0;
}

__global__ void k_hist(const int* __restrict__ dst, int* __restrict__ cnt) {
    int e = blockIdx.x * 256 + threadIdx.x;
    atomicAdd(&cnt[dst[e]], 1);
}

__global__ __launch_bounds__(1024) void k_scan(const int* __restrict__ cnt,
                                               int* __restrict__ offs,
                                               int* __restrict__ nxt,
                                               float* __restrict__ dinv) {
    __shared__ int sh[1024];
    int t = threadIdx.x;
    int base = t * 64;
    int s = 0;
    for (int k = 0; k < 64; ++k) s += cnt[base + k];
    sh[t] = s;
    __syncthreads();
    for (int d = 1; d < 1024; d <<= 1) {
        int v = (t >= d) ? sh[t - d] : 0;
        __syncthreads();
        sh[t] += v;
        __syncthreads();
    }
    int run = (t == 0) ? 0 : sh[t - 1];
    for (int k = 0; k < 64; ++k) {
        int c = cnt[base + k];
        offs[base + k] = run;
        nxt[base + k]  = run;
        dinv[base + k] = rsqrtf((float)(c + 1));
        run += c;
    }
    if (t == 1023) offs[65536] = run;
}

__global__ void k_fill(const int* __restrict__ src, const int* __restrict__ dst,
                       int* __restrict__ nxt, int* __restrict__ csr) {
    int e = blockIdx.x * 256 + threadIdx.x;
    int d = dst[e];
    int p = atomicAdd(&nxt[d], 1);
    csr[p] = src[e];
}

// ---------------------------------------------------------- adjacency powers
__global__ __launch_bounds__(256) void k_adjpow(const float* __restrict__ A,
                                                float* __restrict__ AT) {
    __shared__ float As[4096];
    __shared__ float Bs[4096];
    int t = threadIdx.x;
    for (int q = 0; q < 16; ++q) As[t + 256 * q] = A[t + 256 * q];
    __syncthreads();
    for (int q = 0; q < 16; ++q) {
        int idx = t + 256 * q;
        int n = idx >> 6, j = idx & 63;
        AT[j * 64 + n] = As[idx];
        float acc = 0.f;
        for (int k = 0; k < 64; ++k) acc += As[n * 64 + k] * As[k * 64 + j];
        Bs[idx] = acc;
        AT[4096 + j * 64 + n] = acc;
    }
    __syncthreads();
    for (int q = 0; q < 16; ++q) {
        int idx = t + 256 * q;
        int n = idx >> 6, j = idx & 63;
        float acc = 0.f;
        for (int k = 0; k < 64; ++k) acc += Bs[n * 64 + k] * As[k * 64 + j];
        AT[8192 + j * 64 + n] = acc;
    }
}

// ------------------------------------------------------------- conversions
__global__ void k_cvt_x(const float4* __restrict__ x, ushort4* __restrict__ o) {
    int i = blockIdx.x * 256 + threadIdx.x;
    float4 v = x[i];
    ushort4 u;
    u.x = bfr(v.x); u.y = bfr(v.y); u.z = bfr(v.z); u.w = bfr(v.w);
    o[i] = u;
}

// builds Wt[m][n][k] (bf16, transposed) from the three weight sources
__global__ __launch_bounds__(256) void k_cvt_w(const float* __restrict__ gcnW,
                                               const float* __restrict__ W1,
                                               const float* __restrict__ W2,
                                               unsigned short* __restrict__ Wt) {
    int b = blockIdx.x, t = threadIdx.x;
    int m = b >> 6;
    int idx = (b & 63) * 256 + t;       // dest index within matrix: n*128 + k
    const float* src;
    int N = 128;
    if (m < 12)       src = gcnW + m * 16384;
    else if (m == 12) src = W1;
    else { src = W2; N = 64; if (idx >= 8192) return; }
    int n = idx >> 7, k = idx & 127;
    Wt[m * 16384 + idx] = bfr(src[k * N + n]);
}

// ----------------------------------------------------------------- MFMA GEMM
// C_z[M x (NT*16)] = X[M x 128] @ W_z^T ; X bf16 row-major, Wt bf16 [z][N][K].
// Block: 256 thr = 4 waves; wave handles 32 rows (2 m-tiles of 16).
// A-operand (full K=128) is held in registers across the z loop -> X read once.
template <int NT, int NZ, bool BIAS, bool RELU, bool OUT_BF16>
__global__ __launch_bounds__(256) void k_mfma(const unsigned short* __restrict__ X,
                                              const unsigned short* __restrict__ Wt,
                                              const float* __restrict__ bias,
                                              void* __restrict__ Cout, long cz) {
    int wave = threadIdx.x >> 6, lane = threadIdx.x & 63;
    int l16 = lane & 15, kg = lane >> 4;            // k-group: k0 = kg*8
    long row0 = (long)blockIdx.x * 128 + wave * 32;
    const int NCOL = NT * 16;

    bf8_t a[2][4];
    const unsigned short* xp = X + row0 * 128 + kg * 8;
#pragma unroll
    for (int kb = 0; kb < 4; ++kb) {
        a[0][kb] = *(const bf8_t*)(xp + (long)l16 * 128 + kb * 32);
        a[1][kb] = *(const bf8_t*)(xp + (long)(l16 + 16) * 128 + kb * 32);
    }

#pragma unroll
    for (int z = 0; z < NZ; ++z) {
        f4_t acc[2][NT];
        f4_t zero4 = {0.f, 0.f, 0.f, 0.f};
#pragma unroll
        for (int mt = 0; mt < 2; ++mt)
#pragma unroll
            for (int nt = 0; nt < NT; ++nt) acc[mt][nt] = zero4;

        const unsigned short* wp = Wt + (long)z * 16384 + (long)l16 * 128 + kg * 8;
#pragma unroll
        for (int kb = 0; kb < 4; ++kb) {
#pragma unroll
            for (int nt = 0; nt < NT; ++nt) {
                bf8_t b = *(const bf8_t*)(wp + nt * 16 * 128 + kb * 32);
                acc[0][nt] = __builtin_amdgcn_mfma_f32_16x16x32_bf16(a[0][kb], b, acc[0][nt], 0, 0, 0);
                acc[1][nt] = __builtin_amdgcn_mfma_f32_16x16x32_bf16(a[1][kb], b, acc[1][nt], 0, 0, 0);
            }
        }
        // epilogue: C/D layout col = lane&15, row = kg*4 + r
#pragma unroll
        for (int mt = 0; mt < 2; ++mt)
#pragma unroll
            for (int nt = 0; nt < NT; ++nt)
#pragma unroll
                for (int r = 0; r < 4; ++r) {
                    long row = row0 + mt * 16 + kg * 4 + r;
                    int col = nt * 16 + l16;
                    float v = acc[mt][nt][r];
                    if (BIAS) v += bias[col];
                    if (RELU) v = fmaxf(v, 0.f);
                    long o = (long)z * cz + row * NCOL + col;
                    if (OUT_BF16) ((unsigned short*)Cout)[o] = bfr(v);
                    else          ((float*)Cout)[o] = v;
                }
    }
}

// ---------------------------------------------------------------- meta mix
__global__ __launch_bounds__(256) void k_mix(const float* __restrict__ U,
                                             const float* __restrict__ AT,
                                             float* __restrict__ Y) {
    __shared__ float Us[64 * 256];
    int t = threadIdx.x;
    long c0 = (long)blockIdx.x * 256;
    float acc[64];
#pragma unroll
    for (int n = 0; n < 64; ++n) acc[n] = 0.f;

    for (int i = 0; i < 3; ++i) {
        const float* Ui = U + (long)(i + 1) * NNODES * D;
        __syncthreads();
        for (int j = 0; j < 64; ++j) Us[j * 256 + t] = Ui[(long)j * COLS + c0 + t];
        __syncthreads();
        const float* ATi = AT + i * 4096;
        for (int j = 0; j < 64; ++j) {
            float l = Us[j * 256 + t];
#pragma unroll
            for (int n = 0; n < 64; ++n) acc[n] += ATi[j * 64 + n] * l;
        }
    }
    for (int n = 0; n < 64; ++n)
        Y[(long)n * COLS + c0 + t] = U[(long)n * COLS + c0 + t] + acc[n];
}

// -------------------------------------------------------------- propagation
// half-wave (32 lanes, float4) per node; 2 nodes/wave; edge loop unrolled x2
// -> 4+ independent 512B gathers in flight per wave. Output written as bf16.
__global__ __launch_bounds__(256) void k_prop(const float* __restrict__ Y,
                                              const int* __restrict__ offs,
                                              const int* __restrict__ csr,
                                              const float* __restrict__ dinv,
                                              const float* __restrict__ bias4,
                                              unsigned short* __restrict__ Xout) {
    int v = blockIdx.x * 8 + (threadIdx.x >> 5);
    int lane = threadIdx.x & 31;
    const float4* Y4 = (const float4*)Y;
    float dv = dinv[v];
    float4 self = Y4[(long)v * 32 + lane];
    int e0 = offs[v], e1 = offs[v + 1];
    float ax = 0.f, ay = 0.f, az = 0.f, aw = 0.f;
    int e = e0;
    for (; e + 2 <= e1; e += 2) {
        int u0 = csr[e], u1 = csr[e + 1];
        float d0 = dinv[u0], d1 = dinv[u1];
        float4 y0 = Y4[(long)u0 * 32 + lane];
        float4 y1 = Y4[(long)u1 * 32 + lane];
        ax += d0 * y0.x + d1 * y1.x;
        ay += d0 * y0.y + d1 * y1.y;
        az += d0 * y0.z + d1 * y1.z;
        aw += d0 * y0.w + d1 * y1.w;
    }
    if (e < e1) {
        int u = csr[e];
        float du = dinv[u];
        float4 y = Y4[(long)u * 32 + lane];
        ax += du * y.x; ay += du * y.y; az += du * y.z; aw += du * y.w;
    }
    int f = lane * 4;
    float dvv = dv * dv;
    float b0 = bias4[f + 0] + bias4[128 + f + 0] + bias4[256 + f + 0] + bias4[384 + f + 0];
    float b1 = bias4[f + 1] + bias4[128 + f + 1] + bias4[256 + f + 1] + bias4[384 + f + 1];
    float b2 = bias4[f + 2] + bias4[128 + f + 2] + bias4[256 + f + 2] + bias4[384 + f + 2];
    float b3 = bias4[f + 3] + bias4[128 + f + 3] + bias4[256 + f + 3] + bias4[384 + f + 3];
    ushort4 pk;
    pk.x = bfr(fmaxf(dv * ax + dvv * self.x + b0, 0.f));
    pk.y = bfr(fmaxf(dv * ay + dvv * self.y + b1, 0.f));
    pk.z = bfr(fmaxf(dv * az + dvv * self.z + b2, 0.f));
    pk.w = bfr(fmaxf(dv * aw + dvv * self.w + b3, 0.f));
    *(ushort4*)(Xout + (long)v * 128 + f) = pk;
}

// ------------------------------------------------------------------ launch
extern "C" void kernel_launch(void* const* d_in, const int* in_sizes, int n_in,
                              void* d_out, int out_size, void* d_ws, size_t ws_size,
                              hipStream_t stream) {
    const float* x      = (const float*)d_in[0];
    const int*   subadj = (const int*)d_in[1];
    const float* adj    = (const float*)d_in[2];
    const float* gcn_W  = (const float*)d_in[3];
    const float* gcn_b  = (const float*)d_in[4];
    const float* lin_W1 = (const float*)d_in[5];
    const float* lin_b1 = (const float*)d_in[6];
    const float* lin_W2 = (const float*)d_in[7];
    const float* lin_b2 = (const float*)d_in[8];
    float* out = (float*)d_out;

    const int* e_src = subadj;
    const int* e_dst = subadj + NEDGES;

    char* w = (char*)d_ws;
    int*   cnt  = (int*)w;             w += (size_t)65536 * 4;
    int*   offs = (int*)w;             w += (size_t)65540 * 4;
    int*   nxt  = (int*)w;             w += (size_t)65536 * 4;
    int*   csr  = (int*)w;             w += (size_t)NEDGES * 4;
    float* dinv = (float*)w;           w += (size_t)65536 * 4;
    float* AT   = (float*)w;           w += (size_t)3 * 4096 * 4;
    unsigned short* Xbf = (unsigned short*)w;  w += (size_t)NNODES * D * 2;
    unsigned short* Wt  = (unsigned short*)w;  w += (size_t)14 * 16384 * 2;
    unsigned short* Hbf = (unsigned short*)w;  w += (size_t)NNODES * D * 2;
    float* bufU = (float*)w;           w += (size_t)4 * NNODES * D * 4;
    float* bufY = (float*)w;           w += (size_t)NNODES * D * 4;

    // CSR + degrees + adjacency powers + dtype conversions
    k_zero_cnt<<<256, 256, 0, stream>>>(cnt);
    k_hist<<<NEDGES / 256, 256, 0, stream>>>(e_dst, cnt);
    k_scan<<<1, 1024, 0, stream>>>(cnt, offs, nxt, dinv);
    k_fill<<<NEDGES / 256, 256, 0, stream>>>(e_src, e_dst, nxt, csr);
    k_adjpow<<<1, 256, 0, stream>>>(adj, AT);
    k_cvt_x<<<NNODES * D / 4 / 256, 256, 0, stream>>>((const float4*)x, (ushort4*)Xbf);
    k_cvt_w<<<896, 256, 0, stream>>>(gcn_W, lin_W1, lin_W2, Wt);

    for (int li = 0; li < 3; ++li) {
        k_mfma<8, 4, false, false, false><<<NNODES / 128, 256, 0, stream>>>(
            Xbf, Wt + (size_t)li * 4 * 16384, nullptr, bufU, (long)NNODES * D);
        k_mix<<<COLS / 256, 256, 0, stream>>>(bufU, AT, bufY);
        k_prop<<<NNODES / 8, 256, 0, stream>>>(bufY, offs, csr, dinv,
                                               gcn_b + (size_t)li * 512, Xbf);
    }
    k_mfma<8, 1, true, true, true><<<NNODES / 128, 256, 0, stream>>>(
        Xbf, Wt + (size_t)12 * 16384, lin_b1, Hbf, 0L);
    k_mfma<4, 1, true, false, false><<<NNODES / 128, 256, 0, stream>>>(
        Hbf, Wt + (size_t)13 * 16384, lin_b2, out, 0L);
}

// Round 3
// 759.751 us; speedup vs baseline: 1.6179x; 1.2848x over previous
//
#include <hip/hip_runtime.h>

#define NMETA 64
#define MSUB 1024
#define NNODES 65536          // NMETA*MSUB
#define D 128
#define DOUT 64
#define NEDGES 1048576
#define COLS 131072           // MSUB*D

typedef __attribute__((ext_vector_type(8))) short bf8_t;   // 8 bf16 = 4 VGPRs
typedef __attribute__((ext_vector_type(4))) float f4_t;

__device__ inline unsigned short bfr(float x) {            // fp32 -> bf16 RNE
    unsigned u = __builtin_bit_cast(unsigned, x);
    u += 0x7fffu + ((u >> 16) & 1u);
    return (unsigned short)(u >> 16);
}
__device__ inline float b2f(unsigned short h) {
    return __builtin_bit_cast(float, (unsigned)h << 16);
}

// ---------------------------------------------------------------- CSR build
__global__ void k_zero_cnt(int* __restrict__ cnt) {
    cnt[blockIdx.x * 256 + threadIdx.x] = 0;
}

__global__ void k_hist(const int* __restrict__ dst, int* __restrict__ cnt) {
    int e = blockIdx.x * 256 + threadIdx.x;
    atomicAdd(&cnt[dst[e]], 1);
}

// per-block sums of cnt + dinv = rsqrt(deg+1)
__global__ __launch_bounds__(256) void k_sum_dinv(const int* __restrict__ cnt,
                                                  int* __restrict__ partial,
                                                  float* __restrict__ dinv) {
    __shared__ int sh[256];
    int t = threadIdx.x, i = blockIdx.x * 256 + t;
    int c = cnt[i];
    dinv[i] = rsqrtf((float)(c + 1));
    sh[t] = c;
    __syncthreads();
    for (int s = 128; s > 0; s >>= 1) {
        if (t < s) sh[t] += sh[t + s];
        __syncthreads();
    }
    if (t == 0) partial[blockIdx.x] = sh[0];
}

__global__ __launch_bounds__(256) void k_scan_part(const int* __restrict__ partial,
                                                   int* __restrict__ partoff) {
    __shared__ int sh[256];
    int t = threadIdx.x;
    int v0 = partial[t];
    sh[t] = v0;
    __syncthreads();
    for (int d = 1; d < 256; d <<= 1) {
        int v = (t >= d) ? sh[t - d] : 0;
        __syncthreads();
        sh[t] += v;
        __syncthreads();
    }
    partoff[t] = sh[t] - v0;
}

__global__ __launch_bounds__(256) void k_offs(const int* __restrict__ cnt,
                                              const int* __restrict__ partoff,
                                              int* __restrict__ offs,
                                              int* __restrict__ nxt) {
    __shared__ int sh[256];
    int t = threadIdx.x, i = blockIdx.x * 256 + t;
    int c = cnt[i];
    sh[t] = c;
    __syncthreads();
    for (int d = 1; d < 256; d <<= 1) {
        int v = (t >= d) ? sh[t - d] : 0;
        __syncthreads();
        sh[t] += v;
        __syncthreads();
    }
    int off = partoff[blockIdx.x] + sh[t] - c;
    offs[i] = off;
    nxt[i] = off;
    if (i == NNODES - 1) offs[NNODES] = NEDGES;
}

__global__ void k_fill(const int* __restrict__ src, const int* __restrict__ dst,
                       int* __restrict__ nxt, int* __restrict__ csr) {
    int e = blockIdx.x * 256 + threadIdx.x;
    int d = dst[e];
    int p = atomicAdd(&nxt[d], 1);
    csr[p] = src[e];
}

// ---------------------------------------------------------- adjacency powers
// AT[i][j][n] = (A^(i+1))[n][j]
__global__ __launch_bounds__(256) void k_adjpow(const float* __restrict__ A,
                                                float* __restrict__ AT) {
    __shared__ float As[4096];
    __shared__ float Bs[4096];
    int t = threadIdx.x;
    for (int q = 0; q < 16; ++q) As[t + 256 * q] = A[t + 256 * q];
    __syncthreads();
    for (int q = 0; q < 16; ++q) {
        int idx = t + 256 * q;
        int n = idx >> 6, j = idx & 63;
        AT[j * 64 + n] = As[idx];
        float acc = 0.f;
        for (int k = 0; k < 64; ++k) acc += As[n * 64 + k] * As[k * 64 + j];
        Bs[idx] = acc;
        AT[4096 + j * 64 + n] = acc;
    }
    __syncthreads();
    for (int q = 0; q < 16; ++q) {
        int idx = t + 256 * q;
        int n = idx >> 6, j = idx & 63;
        float acc = 0.f;
        for (int k = 0; k < 64; ++k) acc += Bs[n * 64 + k] * As[k * 64 + j];
        AT[8192 + j * 64 + n] = acc;
    }
}

// ------------------------------------------------------------- conversions
__global__ void k_cvt_x(const float4* __restrict__ x, ushort4* __restrict__ o) {
    int i = blockIdx.x * 256 + threadIdx.x;
    float4 v = x[i];
    ushort4 u;
    u.x = bfr(v.x); u.y = bfr(v.y); u.z = bfr(v.z); u.w = bfr(v.w);
    o[i] = u;
}

// Wt[m][n][k] (bf16, transposed)
__global__ __launch_bounds__(256) void k_cvt_w(const float* __restrict__ gcnW,
                                               const float* __restrict__ W1,
                                               const float* __restrict__ W2,
                                               unsigned short* __restrict__ Wt) {
    int b = blockIdx.x, t = threadIdx.x;
    int m = b >> 6;
    int idx = (b & 63) * 256 + t;
    const float* src;
    int N = 128;
    if (m < 12)       src = gcnW + m * 16384;
    else if (m == 12) src = W1;
    else { src = W2; N = 64; if (idx >= 8192) return; }
    int n = idx >> 7, k = idx & 127;
    Wt[m * 16384 + idx] = bfr(src[k * N + n]);
}

// ---------------------------------------------------------------- meta mix
// Xm[i][n, c] = sum_j A_{i+1}[n, j] * X[j, c]   (bf16 in/out, fp32 acc)
__global__ __launch_bounds__(256) void k_mixX(const unsigned short* __restrict__ X,
                                              const float* __restrict__ AT,
                                              unsigned short* __restrict__ Xm) {
    __shared__ unsigned short Us[64 * 256];
    int t = threadIdx.x;
    long c0 = (long)blockIdx.x * 256;
    // stage 64 x 256 bf16 tile, ushort4 per thread per iter
    for (int q = 0; q < 16; ++q) {
        int row = q * 4 + (t >> 6);
        int col = (t & 63) * 4;
        *(ushort4*)&Us[row * 256 + col] =
            *(const ushort4*)(X + (long)row * COLS + c0 + col);
    }
    __syncthreads();
    for (int i = 0; i < 3; ++i) {
        const float* ATi = AT + i * 4096;
        float acc[64];
#pragma unroll
        for (int n = 0; n < 64; ++n) acc[n] = 0.f;
        for (int j = 0; j < 64; ++j) {
            float l = b2f(Us[j * 256 + t]);
#pragma unroll
            for (int n = 0; n < 64; ++n) acc[n] += ATi[j * 64 + n] * l;
        }
        unsigned short* Xi = Xm + (long)i * NNODES * D;
        for (int n = 0; n < 64; ++n)
            Xi[(long)n * COLS + c0 + t] = bfr(acc[n]);
    }
}

// ----------------------------------------------------------------- fused GEMM
// Y[r, :] = sum_z X_z[r, :128] @ W_z^T   (K=512 via 4 z-chunks), Y bf16.
__global__ __launch_bounds__(256) void k_mgemm(const unsigned short* __restrict__ X0,
                                               const unsigned short* __restrict__ Xm,
                                               const unsigned short* __restrict__ Wt4,
                                               unsigned short* __restrict__ Y) {
    int wave = threadIdx.x >> 6, lane = threadIdx.x & 63;
    int l16 = lane & 15, kg = lane >> 4;
    long row0 = (long)blockIdx.x * 128 + wave * 32;

    f4_t acc[2][8];
    f4_t zero4 = {0.f, 0.f, 0.f, 0.f};
#pragma unroll
    for (int mt = 0; mt < 2; ++mt)
#pragma unroll
        for (int nt = 0; nt < 8; ++nt) acc[mt][nt] = zero4;

#pragma unroll
    for (int z = 0; z < 4; ++z) {
        const unsigned short* Xz = (z == 0) ? X0 : Xm + (long)(z - 1) * NNODES * D;
        const unsigned short* xp = Xz + row0 * 128 + kg * 8;
        const unsigned short* wp = Wt4 + z * 16384 + (long)l16 * 128 + kg * 8;
#pragma unroll
        for (int kb = 0; kb < 4; ++kb) {
            bf8_t a0 = *(const bf8_t*)(xp + (long)l16 * 128 + kb * 32);
            bf8_t a1 = *(const bf8_t*)(xp + (long)(l16 + 16) * 128 + kb * 32);
#pragma unroll
            for (int nt = 0; nt < 8; ++nt) {
                bf8_t b = *(const bf8_t*)(wp + nt * 16 * 128 + kb * 32);
                acc[0][nt] = __builtin_amdgcn_mfma_f32_16x16x32_bf16(a0, b, acc[0][nt], 0, 0, 0);
                acc[1][nt] = __builtin_amdgcn_mfma_f32_16x16x32_bf16(a1, b, acc[1][nt], 0, 0, 0);
            }
        }
    }
#pragma unroll
    for (int mt = 0; mt < 2; ++mt)
#pragma unroll
        for (int nt = 0; nt < 8; ++nt)
#pragma unroll
            for (int r = 0; r < 4; ++r) {
                long row = row0 + mt * 16 + kg * 4 + r;
                int col = nt * 16 + l16;
                Y[row * 128 + col] = bfr(acc[mt][nt][r]);
            }
}

// ----------------------------------------------------------------- MFMA GEMM (MLP)
template <int NT, bool RELU, bool OUT_BF16>
__global__ __launch_bounds__(256) void k_mfma(const unsigned short* __restrict__ X,
                                              const unsigned short* __restrict__ Wt,
                                              const float* __restrict__ bias,
                                              void* __restrict__ Cout) {
    int wave = threadIdx.x >> 6, lane = threadIdx.x & 63;
    int l16 = lane & 15, kg = lane >> 4;
    long row0 = (long)blockIdx.x * 128 + wave * 32;
    const int NCOL = NT * 16;

    bf8_t a[2][4];
    const unsigned short* xp = X + row0 * 128 + kg * 8;
#pragma unroll
    for (int kb = 0; kb < 4; ++kb) {
        a[0][kb] = *(const bf8_t*)(xp + (long)l16 * 128 + kb * 32);
        a[1][kb] = *(const bf8_t*)(xp + (long)(l16 + 16) * 128 + kb * 32);
    }
    f4_t acc[2][NT];
    f4_t zero4 = {0.f, 0.f, 0.f, 0.f};
#pragma unroll
    for (int mt = 0; mt < 2; ++mt)
#pragma unroll
        for (int nt = 0; nt < NT; ++nt) acc[mt][nt] = zero4;

    const unsigned short* wp = Wt + (long)l16 * 128 + kg * 8;
#pragma unroll
    for (int kb = 0; kb < 4; ++kb)
#pragma unroll
        for (int nt = 0; nt < NT; ++nt) {
            bf8_t b = *(const bf8_t*)(wp + nt * 16 * 128 + kb * 32);
            acc[0][nt] = __builtin_amdgcn_mfma_f32_16x16x32_bf16(a[0][kb], b, acc[0][nt], 0, 0, 0);
            acc[1][nt] = __builtin_amdgcn_mfma_f32_16x16x32_bf16(a[1][kb], b, acc[1][nt], 0, 0, 0);
        }
#pragma unroll
    for (int mt = 0; mt < 2; ++mt)
#pragma unroll
        for (int nt = 0; nt < NT; ++nt)
#pragma unroll
            for (int r = 0; r < 4; ++r) {
                long row = row0 + mt * 16 + kg * 4 + r;
                int col = nt * 16 + l16;
                float v = acc[mt][nt][r] + bias[col];
                if (RELU) v = fmaxf(v, 0.f);
                long o = row * NCOL + col;
                if (OUT_BF16) ((unsigned short*)Cout)[o] = bfr(v);
                else          ((float*)Cout)[o] = v;
            }
}

// -------------------------------------------------------------- propagation
// bf16 Y rows (256 B); half-wave per node; csr batch-load + x4 unroll.
__global__ __launch_bounds__(256) void k_prop(const unsigned short* __restrict__ Y,
                                              const int* __restrict__ offs,
                                              const int* __restrict__ csr,
                                              const float* __restrict__ dinv,
                                              const float* __restrict__ bias4,
                                              unsigned short* __restrict__ Xout) {
    int v = blockIdx.x * 8 + (threadIdx.x >> 5);
    int lane = threadIdx.x & 31;
    const ushort4* Y4 = (const ushort4*)Y;
    float dv = dinv[v];
    ushort4 s4 = Y4[(long)v * 32 + lane];
    int e0 = offs[v], e1 = offs[v + 1];
    float ax = 0.f, ay = 0.f, az = 0.f, aw = 0.f;
    int e = e0;
    for (; e + 4 <= e1; e += 4) {
        int u0 = csr[e], u1 = csr[e + 1], u2 = csr[e + 2], u3 = csr[e + 3];
        float d0 = dinv[u0], d1 = dinv[u1], d2 = dinv[u2], d3 = dinv[u3];
        ushort4 y0 = Y4[(long)u0 * 32 + lane];
        ushort4 y1 = Y4[(long)u1 * 32 + lane];
        ushort4 y2 = Y4[(long)u2 * 32 + lane];
        ushort4 y3 = Y4[(long)u3 * 32 + lane];
        ax += d0 * b2f(y0.x) + d1 * b2f(y1.x) + d2 * b2f(y2.x) + d3 * b2f(y3.x);
        ay += d0 * b2f(y0.y) + d1 * b2f(y1.y) + d2 * b2f(y2.y) + d3 * b2f(y3.y);
        az += d0 * b2f(y0.z) + d1 * b2f(y1.z) + d2 * b2f(y2.z) + d3 * b2f(y3.z);
        aw += d0 * b2f(y0.w) + d1 * b2f(y1.w) + d2 * b2f(y2.w) + d3 * b2f(y3.w);
    }
    for (; e < e1; ++e) {
        int u = csr[e];
        float du = dinv[u];
        ushort4 y = Y4[(long)u * 32 + lane];
        ax += du * b2f(y.x); ay += du * b2f(y.y);
        az += du * b2f(y.z); aw += du * b2f(y.w);
    }
    int f = lane * 4;
    float dvv = dv * dv;
    float b0 = bias4[f + 0] + bias4[128 + f + 0] + bias4[256 + f + 0] + bias4[384 + f + 0];
    float b1 = bias4[f + 1] + bias4[128 + f + 1] + bias4[256 + f + 1] + bias4[384 + f + 1];
    float b2 = bias4[f + 2] + bias4[128 + f + 2] + bias4[256 + f + 2] + bias4[384 + f + 2];
    float b3 = bias4[f + 3] + bias4[128 + f + 3] + bias4[256 + f + 3] + bias4[384 + f + 3];
    ushort4 pk;
    pk.x = bfr(fmaxf(dv * ax + dvv * b2f(s4.x) + b0, 0.f));
    pk.y = bfr(fmaxf(dv * ay + dvv * b2f(s4.y) + b1, 0.f));
    pk.z = bfr(fmaxf(dv * az + dvv * b2f(s4.z) + b2, 0.f));
    pk.w = bfr(fmaxf(dv * aw + dvv * b2f(s4.w) + b3, 0.f));
    *(ushort4*)(Xout + (long)v * 128 + f) = pk;
}

// ------------------------------------------------------------------ launch
extern "C" void kernel_launch(void* const* d_in, const int* in_sizes, int n_in,
                              void* d_out, int out_size, void* d_ws, size_t ws_size,
                              hipStream_t stream) {
    const float* x      = (const float*)d_in[0];
    const int*   subadj = (const int*)d_in[1];
    const float* adj    = (const float*)d_in[2];
    const float* gcn_W  = (const float*)d_in[3];
    const float* gcn_b  = (const float*)d_in[4];
    const float* lin_W1 = (const float*)d_in[5];
    const float* lin_b1 = (const float*)d_in[6];
    const float* lin_W2 = (const float*)d_in[7];
    const float* lin_b2 = (const float*)d_in[8];
    float* out = (float*)d_out;

    const int* e_src = subadj;
    const int* e_dst = subadj + NEDGES;

    char* w = (char*)d_ws;
    int*   cnt     = (int*)w;   w += (size_t)65536 * 4;
    int*   partial = (int*)w;   w += (size_t)256 * 4;
    int*   partoff = (int*)w;   w += (size_t)256 * 4;
    int*   offs    = (int*)w;   w += (size_t)65540 * 4;
    int*   nxt     = (int*)w;   w += (size_t)65536 * 4;
    int*   csr     = (int*)w;   w += (size_t)NEDGES * 4;
    float* dinv    = (float*)w; w += (size_t)65536 * 4;
    float* AT      = (float*)w; w += (size_t)3 * 4096 * 4;
    unsigned short* Xbf = (unsigned short*)w; w += (size_t)NNODES * D * 2;
    unsigned short* Xm  = (unsigned short*)w; w += (size_t)3 * NNODES * D * 2;
    unsigned short* Ybf = (unsigned short*)w; w += (size_t)NNODES * D * 2;
    unsigned short* Wt  = (unsigned short*)w; w += (size_t)14 * 16384 * 2;
    unsigned short* Hbf = (unsigned short*)w; w += (size_t)NNODES * D * 2;

    k_zero_cnt<<<256, 256, 0, stream>>>(cnt);
    k_hist<<<NEDGES / 256, 256, 0, stream>>>(e_dst, cnt);
    k_sum_dinv<<<256, 256, 0, stream>>>(cnt, partial, dinv);
    k_scan_part<<<1, 256, 0, stream>>>(partial, partoff);
    k_offs<<<256, 256, 0, stream>>>(cnt, partoff, offs, nxt);
    k_fill<<<NEDGES / 256, 256, 0, stream>>>(e_src, e_dst, nxt, csr);
    k_adjpow<<<1, 256, 0, stream>>>(adj, AT);
    k_cvt_x<<<NNODES * D / 4 / 256, 256, 0, stream>>>((const float4*)x, (ushort4*)Xbf);
    k_cvt_w<<<896, 256, 0, stream>>>(gcn_W, lin_W1, lin_W2, Wt);

    for (int li = 0; li < 3; ++li) {
        k_mixX<<<COLS / 256, 256, 0, stream>>>(Xbf, AT, Xm);
        k_mgemm<<<NNODES / 128, 256, 0, stream>>>(Xbf, Xm, Wt + (size_t)li * 4 * 16384, Ybf);
        k_prop<<<NNODES / 8, 256, 0, stream>>>(Ybf, offs, csr, dinv,
                                               gcn_b + (size_t)li * 512, Xbf);
    }
    k_mfma<8, true, true><<<NNODES / 128, 256, 0, stream>>>(
        Xbf, Wt + (size_t)12 * 16384, lin_b1, Hbf);
    k_mfma<4, false, false><<<NNODES / 128, 256, 0, stream>>>(
        Hbf, Wt + (size_t)13 * 16384, lin_b2, out);
}

// Round 4
// 635.911 us; speedup vs baseline: 1.9329x; 1.1947x over previous
//
#include <hip/hip_runtime.h>

#define NMETA 64
#define MSUB 1024
#define NNODES 65536          // NMETA*MSUB
#define D 128
#define DOUT 64
#define NEDGES 1048576
#define COLS 131072           // MSUB*D

typedef __attribute__((ext_vector_type(8))) short bf8_t;   // 8 bf16 = 4 VGPRs
typedef __attribute__((ext_vector_type(4))) float f4_t;

__device__ inline unsigned short bfr(float x) {            // fp32 -> bf16 RNE
    unsigned u = __builtin_bit_cast(unsigned, x);
    u += 0x7fffu + ((u >> 16) & 1u);
    return (unsigned short)(u >> 16);
}
__device__ inline float b2f(unsigned short h) {
    return __builtin_bit_cast(float, (unsigned)h << 16);
}
__device__ inline void unpack8(uint4 u, float* f) {        // 8 bf16 from 16B
    f[0] = __builtin_bit_cast(float, u.x << 16);
    f[1] = __builtin_bit_cast(float, u.x & 0xffff0000u);
    f[2] = __builtin_bit_cast(float, u.y << 16);
    f[3] = __builtin_bit_cast(float, u.y & 0xffff0000u);
    f[4] = __builtin_bit_cast(float, u.z << 16);
    f[5] = __builtin_bit_cast(float, u.z & 0xffff0000u);
    f[6] = __builtin_bit_cast(float, u.w << 16);
    f[7] = __builtin_bit_cast(float, u.w & 0xffff0000u);
}

// ---------------------------------------------------------------- CSR build
__global__ void k_zero_cnt(int* __restrict__ cnt) {
    cnt[blockIdx.x * 256 + threadIdx.x] = 0;
}

__global__ void k_hist(const int* __restrict__ dst, int* __restrict__ cnt) {
    int e = blockIdx.x * 256 + threadIdx.x;
    atomicAdd(&cnt[dst[e]], 1);
}

__global__ __launch_bounds__(256) void k_sum_dinv(const int* __restrict__ cnt,
                                                  int* __restrict__ partial,
                                                  float* __restrict__ dinv) {
    __shared__ int sh[256];
    int t = threadIdx.x, i = blockIdx.x * 256 + t;
    int c = cnt[i];
    dinv[i] = rsqrtf((float)(c + 1));
    sh[t] = c;
    __syncthreads();
    for (int s = 128; s > 0; s >>= 1) {
        if (t < s) sh[t] += sh[t + s];
        __syncthreads();
    }
    if (t == 0) partial[blockIdx.x] = sh[0];
}

__global__ __launch_bounds__(256) void k_scan_part(const int* __restrict__ partial,
                                                   int* __restrict__ partoff) {
    __shared__ int sh[256];
    int t = threadIdx.x;
    int v0 = partial[t];
    sh[t] = v0;
    __syncthreads();
    for (int d = 1; d < 256; d <<= 1) {
        int v = (t >= d) ? sh[t - d] : 0;
        __syncthreads();
        sh[t] += v;
        __syncthreads();
    }
    partoff[t] = sh[t] - v0;
}

__global__ __launch_bounds__(256) void k_offs(const int* __restrict__ cnt,
                                              const int* __restrict__ partoff,
                                              int* __restrict__ offs,
                                              int* __restrict__ nxt) {
    __shared__ int sh[256];
    int t = threadIdx.x, i = blockIdx.x * 256 + t;
    int c = cnt[i];
    sh[t] = c;
    __syncthreads();
    for (int d = 1; d < 256; d <<= 1) {
        int v = (t >= d) ? sh[t - d] : 0;
        __syncthreads();
        sh[t] += v;
        __syncthreads();
    }
    int off = partoff[blockIdx.x] + sh[t] - c;
    offs[i] = off;
    nxt[i] = off;
    if (i == NNODES - 1) offs[NNODES] = NEDGES;
}

__global__ void k_fill(const int* __restrict__ src, const int* __restrict__ dst,
                       int* __restrict__ nxt, int* __restrict__ csr) {
    int e = blockIdx.x * 256 + threadIdx.x;
    int d = dst[e];
    int p = atomicAdd(&nxt[d], 1);
    csr[p] = src[e];
}

// ---------------------------------------------------------- adjacency powers
// Ab[i][n][j] = bf16((A^(i+1))[n][j]), row-major — MFMA A-operand source
__global__ __launch_bounds__(256) void k_adjpow(const float* __restrict__ A,
                                                unsigned short* __restrict__ Ab) {
    __shared__ float As[4096];
    __shared__ float Bs[4096];
    int t = threadIdx.x;
    for (int q = 0; q < 16; ++q) As[t + 256 * q] = A[t + 256 * q];
    __syncthreads();
    for (int q = 0; q < 16; ++q) {
        int idx = t + 256 * q;
        int n = idx >> 6, j = idx & 63;
        Ab[idx] = bfr(As[idx]);
        float acc = 0.f;
        for (int k = 0; k < 64; ++k) acc += As[n * 64 + k] * As[k * 64 + j];
        Bs[idx] = acc;
        Ab[4096 + idx] = bfr(acc);
    }
    __syncthreads();
    for (int q = 0; q < 16; ++q) {
        int idx = t + 256 * q;
        int n = idx >> 6, j = idx & 63;
        float acc = 0.f;
        for (int k = 0; k < 64; ++k) acc += Bs[n * 64 + k] * As[k * 64 + j];
        Ab[8192 + idx] = bfr(acc);
    }
}

// ------------------------------------------------------------- conversions
__global__ void k_cvt_x(const float4* __restrict__ x, ushort4* __restrict__ o) {
    int i = blockIdx.x * 256 + threadIdx.x;
    float4 v = x[i];
    ushort4 u;
    u.x = bfr(v.x); u.y = bfr(v.y); u.z = bfr(v.z); u.w = bfr(v.w);
    o[i] = u;
}

// Wt[m][n][k] (bf16, transposed)
__global__ __launch_bounds__(256) void k_cvt_w(const float* __restrict__ gcnW,
                                               const float* __restrict__ W1,
                                               const float* __restrict__ W2,
                                               unsigned short* __restrict__ Wt) {
    int b = blockIdx.x, t = threadIdx.x;
    int m = b >> 6;
    int idx = (b & 63) * 256 + t;
    const float* src;
    int N = 128;
    if (m < 12)       src = gcnW + m * 16384;
    else if (m == 12) src = W1;
    else { src = W2; N = 64; if (idx >= 8192) return; }
    int n = idx >> 7, k = idx & 127;
    Wt[m * 16384 + idx] = bfr(src[k * N + n]);
}

// ---------------------------------------------------------------- meta mix (MFMA)
// Xm[i][n, c] = sum_j A_{i+1}[n, j] * X[j, c]; per block: 256-column tile,
// X tile staged in LDS (pad 258), A-power fragments preloaded from global.
#define CPAD 258
__global__ __launch_bounds__(256) void k_mixX(const unsigned short* __restrict__ X,
                                              const unsigned short* __restrict__ Ab,
                                              unsigned short* __restrict__ Xm) {
    __shared__ unsigned short Us[64 * CPAD];
    int t = threadIdx.x;
    long c0 = (long)blockIdx.x * 256;
    int wave = t >> 6, lane = t & 63;
    int l16 = lane & 15, kg = lane >> 4;
    // stage X[0..63][c0..c0+255]
    {
        int col = (t & 63) * 4;
        for (int q = 0; q < 16; ++q) {
            int row = q * 4 + (t >> 6);
            *(ushort4*)&Us[row * CPAD + col] =
                *(const ushort4*)(X + (long)row * COLS + c0 + col);
        }
    }
    // A fragments: a[i][kb] covers A_{i+1}[mt*16+l16][kb*32+kg*8 ..+8], mt = wave
    bf8_t a[3][2];
#pragma unroll
    for (int i = 0; i < 3; ++i)
#pragma unroll
        for (int kb = 0; kb < 2; ++kb)
            a[i][kb] = *(const bf8_t*)(Ab + i * 4096 + (wave * 16 + l16) * 64 +
                                       kb * 32 + kg * 8);
    __syncthreads();
    f4_t zero4 = {0.f, 0.f, 0.f, 0.f};
    for (int cs = 0; cs < 16; ++cs) {
        int cc = cs * 16 + l16;
        bf8_t b0, b1;
#pragma unroll
        for (int jj = 0; jj < 8; ++jj) {
            b0[jj] = (short)Us[(kg * 8 + jj) * CPAD + cc];
            b1[jj] = (short)Us[(32 + kg * 8 + jj) * CPAD + cc];
        }
        f4_t acc0 = zero4, acc1 = zero4, acc2 = zero4;
        acc0 = __builtin_amdgcn_mfma_f32_16x16x32_bf16(a[0][0], b0, acc0, 0, 0, 0);
        acc1 = __builtin_amdgcn_mfma_f32_16x16x32_bf16(a[1][0], b0, acc1, 0, 0, 0);
        acc2 = __builtin_amdgcn_mfma_f32_16x16x32_bf16(a[2][0], b0, acc2, 0, 0, 0);
        acc0 = __builtin_amdgcn_mfma_f32_16x16x32_bf16(a[0][1], b1, acc0, 0, 0, 0);
        acc1 = __builtin_amdgcn_mfma_f32_16x16x32_bf16(a[1][1], b1, acc1, 0, 0, 0);
        acc2 = __builtin_amdgcn_mfma_f32_16x16x32_bf16(a[2][1], b1, acc2, 0, 0, 0);
        // D layout: col = lane&15 (= c), row = kg*4 + r (= n within tile)
#pragma unroll
        for (int r = 0; r < 4; ++r) {
            long n = wave * 16 + kg * 4 + r;
            long o = n * COLS + c0 + cc;
            Xm[o]                       = bfr(acc0[r]);
            Xm[(long)NNODES * D + o]    = bfr(acc1[r]);
            Xm[(long)2 * NNODES * D + o] = bfr(acc2[r]);
        }
    }
}

// ----------------------------------------------------------------- fused GEMM
// Y[r, :] = sum_z X_z[r, :128] @ W_z^T   (K=512 via 4 z-chunks), Y bf16.
__global__ __launch_bounds__(256) void k_mgemm(const unsigned short* __restrict__ X0,
                                               const unsigned short* __restrict__ Xm,
                                               const unsigned short* __restrict__ Wt4,
                                               unsigned short* __restrict__ Y) {
    int wave = threadIdx.x >> 6, lane = threadIdx.x & 63;
    int l16 = lane & 15, kg = lane >> 4;
    long row0 = (long)blockIdx.x * 128 + wave * 32;

    f4_t acc[2][8];
    f4_t zero4 = {0.f, 0.f, 0.f, 0.f};
#pragma unroll
    for (int mt = 0; mt < 2; ++mt)
#pragma unroll
        for (int nt = 0; nt < 8; ++nt) acc[mt][nt] = zero4;

#pragma unroll
    for (int z = 0; z < 4; ++z) {
        const unsigned short* Xz = (z == 0) ? X0 : Xm + (long)(z - 1) * NNODES * D;
        const unsigned short* xp = Xz + row0 * 128 + kg * 8;
        const unsigned short* wp = Wt4 + z * 16384 + (long)l16 * 128 + kg * 8;
#pragma unroll
        for (int kb = 0; kb < 4; ++kb) {
            bf8_t a0 = *(const bf8_t*)(xp + (long)l16 * 128 + kb * 32);
            bf8_t a1 = *(const bf8_t*)(xp + (long)(l16 + 16) * 128 + kb * 32);
#pragma unroll
            for (int nt = 0; nt < 8; ++nt) {
                bf8_t b = *(const bf8_t*)(wp + nt * 16 * 128 + kb * 32);
                acc[0][nt] = __builtin_amdgcn_mfma_f32_16x16x32_bf16(a0, b, acc[0][nt], 0, 0, 0);
                acc[1][nt] = __builtin_amdgcn_mfma_f32_16x16x32_bf16(a1, b, acc[1][nt], 0, 0, 0);
            }
        }
    }
#pragma unroll
    for (int mt = 0; mt < 2; ++mt)
#pragma unroll
        for (int nt = 0; nt < 8; ++nt)
#pragma unroll
            for (int r = 0; r < 4; ++r) {
                long row = row0 + mt * 16 + kg * 4 + r;
                int col = nt * 16 + l16;
                Y[row * 128 + col] = bfr(acc[mt][nt][r]);
            }
}

// ----------------------------------------------------------------- MFMA GEMM (MLP)
template <int NT, bool RELU, bool OUT_BF16>
__global__ __launch_bounds__(256) void k_mfma(const unsigned short* __restrict__ X,
                                              const unsigned short* __restrict__ Wt,
                                              const float* __restrict__ bias,
                                              void* __restrict__ Cout) {
    int wave = threadIdx.x >> 6, lane = threadIdx.x & 63;
    int l16 = lane & 15, kg = lane >> 4;
    long row0 = (long)blockIdx.x * 128 + wave * 32;
    const int NCOL = NT * 16;

    bf8_t a[2][4];
    const unsigned short* xp = X + row0 * 128 + kg * 8;
#pragma unroll
    for (int kb = 0; kb < 4; ++kb) {
        a[0][kb] = *(const bf8_t*)(xp + (long)l16 * 128 + kb * 32);
        a[1][kb] = *(const bf8_t*)(xp + (long)(l16 + 16) * 128 + kb * 32);
    }
    f4_t acc[2][NT];
    f4_t zero4 = {0.f, 0.f, 0.f, 0.f};
#pragma unroll
    for (int mt = 0; mt < 2; ++mt)
#pragma unroll
        for (int nt = 0; nt < NT; ++nt) acc[mt][nt] = zero4;

    const unsigned short* wp = Wt + (long)l16 * 128 + kg * 8;
#pragma unroll
    for (int kb = 0; kb < 4; ++kb)
#pragma unroll
        for (int nt = 0; nt < NT; ++nt) {
            bf8_t b = *(const bf8_t*)(wp + nt * 16 * 128 + kb * 32);
            acc[0][nt] = __builtin_amdgcn_mfma_f32_16x16x32_bf16(a[0][kb], b, acc[0][nt], 0, 0, 0);
            acc[1][nt] = __builtin_amdgcn_mfma_f32_16x16x32_bf16(a[1][kb], b, acc[1][nt], 0, 0, 0);
        }
#pragma unroll
    for (int mt = 0; mt < 2; ++mt)
#pragma unroll
        for (int nt = 0; nt < NT; ++nt)
#pragma unroll
            for (int r = 0; r < 4; ++r) {
                long row = row0 + mt * 16 + kg * 4 + r;
                int col = nt * 16 + l16;
                float v = acc[mt][nt][r] + bias[col];
                if (RELU) v = fmaxf(v, 0.f);
                long o = row * NCOL + col;
                if (OUT_BF16) ((unsigned short*)Cout)[o] = bfr(v);
                else          ((float*)Cout)[o] = v;
            }
}

// -------------------------------------------------------------- propagation
// one node per wave; 4 quarter-waves interleave the edge list (stride 4,
// unroll x2 -> 8 row-gathers in flight); shfl_xor(16/32) reduction.
__global__ __launch_bounds__(256) void k_prop(const unsigned short* __restrict__ Y,
                                              const int* __restrict__ offs,
                                              const int* __restrict__ csr,
                                              const float* __restrict__ dinv,
                                              const float* __restrict__ bias4,
                                              unsigned short* __restrict__ Xout) {
    int wid = threadIdx.x >> 6;
    int lane = threadIdx.x & 63;
    int q = lane >> 4;
    int l = lane & 15;
    int v = blockIdx.x * 4 + wid;
    const uint4* Y4 = (const uint4*)Y;
    int e0 = offs[v], e1 = offs[v + 1];
    float acc[8];
#pragma unroll
    for (int k = 0; k < 8; ++k) acc[k] = 0.f;

    int e = e0 + q;
    for (; e + 4 < e1; e += 8) {
        int u0 = csr[e], u1 = csr[e + 4];
        float d0 = dinv[u0], d1 = dinv[u1];
        uint4 y0 = Y4[(long)u0 * 16 + l];
        uint4 y1 = Y4[(long)u1 * 16 + l];
        float f0[8], f1[8];
        unpack8(y0, f0);
        unpack8(y1, f1);
#pragma unroll
        for (int k = 0; k < 8; ++k) acc[k] += d0 * f0[k] + d1 * f1[k];
    }
    if (e < e1) {
        int u = csr[e];
        float du = dinv[u];
        uint4 y = Y4[(long)u * 16 + l];
        float f[8];
        unpack8(y, f);
#pragma unroll
        for (int k = 0; k < 8; ++k) acc[k] += du * f[k];
    }
#pragma unroll
    for (int k = 0; k < 8; ++k) {
        acc[k] += __shfl_xor(acc[k], 32, 64);
        acc[k] += __shfl_xor(acc[k], 16, 64);
    }
    if (q == 0) {
        float dv = dinv[v];
        float dvv = dv * dv;
        uint4 s = Y4[(long)v * 16 + l];
        float sf[8];
        unpack8(s, sf);
        float bs[8];
#pragma unroll
        for (int k = 0; k < 8; ++k) bs[k] = 0.f;
#pragma unroll
        for (int p = 0; p < 4; ++p) {
            float4 blo = *(const float4*)(bias4 + p * 128 + l * 8);
            float4 bhi = *(const float4*)(bias4 + p * 128 + l * 8 + 4);
            bs[0] += blo.x; bs[1] += blo.y; bs[2] += blo.z; bs[3] += blo.w;
            bs[4] += bhi.x; bs[5] += bhi.y; bs[6] += bhi.z; bs[7] += bhi.w;
        }
        unsigned r[8];
#pragma unroll
        for (int k = 0; k < 8; ++k)
            r[k] = bfr(fmaxf(dv * acc[k] + dvv * sf[k] + bs[k], 0.f));
        uint4 pk;
        pk.x = (r[1] << 16) | r[0];
        pk.y = (r[3] << 16) | r[2];
        pk.z = (r[5] << 16) | r[4];
        pk.w = (r[7] << 16) | r[6];
        ((uint4*)Xout)[(long)v * 16 + l] = pk;
    }
}

// ------------------------------------------------------------------ launch
extern "C" void kernel_launch(void* const* d_in, const int* in_sizes, int n_in,
                              void* d_out, int out_size, void* d_ws, size_t ws_size,
                              hipStream_t stream) {
    const float* x      = (const float*)d_in[0];
    const int*   subadj = (const int*)d_in[1];
    const float* adj    = (const float*)d_in[2];
    const float* gcn_W  = (const float*)d_in[3];
    const float* gcn_b  = (const float*)d_in[4];
    const float* lin_W1 = (const float*)d_in[5];
    const float* lin_b1 = (const float*)d_in[6];
    const float* lin_W2 = (const float*)d_in[7];
    const float* lin_b2 = (const float*)d_in[8];
    float* out = (float*)d_out;

    const int* e_src = subadj;
    const int* e_dst = subadj + NEDGES;

    char* w = (char*)d_ws;
    int*   cnt     = (int*)w;   w += (size_t)65536 * 4;
    int*   partial = (int*)w;   w += (size_t)256 * 4;
    int*   partoff = (int*)w;   w += (size_t)256 * 4;
    int*   offs    = (int*)w;   w += (size_t)65540 * 4;
    int*   nxt     = (int*)w;   w += (size_t)65536 * 4;
    int*   csr     = (int*)w;   w += (size_t)NEDGES * 4;
    float* dinv    = (float*)w; w += (size_t)65536 * 4;
    unsigned short* Ab  = (unsigned short*)w; w += (size_t)3 * 4096 * 2;
    unsigned short* Xbf = (unsigned short*)w; w += (size_t)NNODES * D * 2;
    unsigned short* Xm  = (unsigned short*)w; w += (size_t)3 * NNODES * D * 2;
    unsigned short* Ybf = (unsigned short*)w; w += (size_t)NNODES * D * 2;
    unsigned short* Wt  = (unsigned short*)w; w += (size_t)14 * 16384 * 2;
    unsigned short* Hbf = (unsigned short*)w; w += (size_t)NNODES * D * 2;

    k_zero_cnt<<<256, 256, 0, stream>>>(cnt);
    k_hist<<<NEDGES / 256, 256, 0, stream>>>(e_dst, cnt);
    k_sum_dinv<<<256, 256, 0, stream>>>(cnt, partial, dinv);
    k_scan_part<<<1, 256, 0, stream>>>(partial, partoff);
    k_offs<<<256, 256, 0, stream>>>(cnt, partoff, offs, nxt);
    k_fill<<<NEDGES / 256, 256, 0, stream>>>(e_src, e_dst, nxt, csr);
    k_adjpow<<<1, 256, 0, stream>>>(adj, Ab);
    k_cvt_x<<<NNODES * D / 4 / 256, 256, 0, stream>>>((const float4*)x, (ushort4*)Xbf);
    k_cvt_w<<<896, 256, 0, stream>>>(gcn_W, lin_W1, lin_W2, Wt);

    for (int li = 0; li < 3; ++li) {
        k_mixX<<<COLS / 256, 256, 0, stream>>>(Xbf, Ab, Xm);
        k_mgemm<<<NNODES / 128, 256, 0, stream>>>(Xbf, Xm, Wt + (size_t)li * 4 * 16384, Ybf);
        k_prop<<<NNODES / 4, 256, 0, stream>>>(Ybf, offs, csr, dinv,
                                               gcn_b + (size_t)li * 512, Xbf);
    }
    k_mfma<8, true, true><<<NNODES / 128, 256, 0, stream>>>(
        Xbf, Wt + (size_t)12 * 16384, lin_b1, Hbf);
    k_mfma<4, false, false><<<NNODES / 128, 256, 0, stream>>>(
        Hbf, Wt + (size_t)13 * 16384, lin_b2, out);
}

// Round 5
// 525.600 us; speedup vs baseline: 2.3386x; 1.2099x over previous
//
#include <hip/hip_runtime.h>

#define NMETA 64
#define MSUB 1024
#define NNODES 65536          // NMETA*MSUB
#define D 128
#define DOUT 64
#define NEDGES 1048576
#define COLS 131072           // MSUB*D
#define BCAP 5120             // LDS capacity per bucket (mean 4096, sigma 64)

typedef __attribute__((ext_vector_type(8))) short bf8_t;   // 8 bf16 = 4 VGPRs
typedef __attribute__((ext_vector_type(4))) float f4_t;

__device__ inline unsigned short bfr(float x) {            // fp32 -> bf16 RNE
    unsigned u = __builtin_bit_cast(unsigned, x);
    u += 0x7fffu + ((u >> 16) & 1u);
    return (unsigned short)(u >> 16);
}
__device__ inline float b2f(unsigned short h) {
    return __builtin_bit_cast(float, (unsigned)h << 16);
}
__device__ inline void unpack8(uint4 u, float* f) {        // 8 bf16 from 16B
    f[0] = __builtin_bit_cast(float, u.x << 16);
    f[1] = __builtin_bit_cast(float, u.x & 0xffff0000u);
    f[2] = __builtin_bit_cast(float, u.y << 16);
    f[3] = __builtin_bit_cast(float, u.y & 0xffff0000u);
    f[4] = __builtin_bit_cast(float, u.z << 16);
    f[5] = __builtin_bit_cast(float, u.z & 0xffff0000u);
    f[6] = __builtin_bit_cast(float, u.w << 16);
    f[7] = __builtin_bit_cast(float, u.w & 0xffff0000u);
}

// ------------------------------------------------------- CSR via 256-bucket radix
__global__ void k_zero256(int* __restrict__ p) { p[threadIdx.x] = 0; }

// per-wg histogram of 4096 edges into 256 buckets (dst>>8); reserve segment
__global__ __launch_bounds__(256) void k_bhist(const int* __restrict__ dst,
                                               int* __restrict__ bcnt,
                                               int* __restrict__ wgoff) {
    __shared__ int c[256];
    int t = threadIdx.x, w = blockIdx.x;
    c[t] = 0;
    __syncthreads();
    const int* dp = dst + w * 4096;
    for (int k = 0; k < 16; ++k) atomicAdd(&c[dp[k * 256 + t] >> 8], 1);
    __syncthreads();
    wgoff[w * 256 + t] = atomicAdd(&bcnt[t], c[t]);
}

__global__ __launch_bounds__(256) void k_bscan(const int* __restrict__ bcnt,
                                               int* __restrict__ bbase) {
    __shared__ int sh[256];
    int t = threadIdx.x;
    int v = bcnt[t];
    sh[t] = v;
    __syncthreads();
    for (int d = 1; d < 256; d <<= 1) {
        int x = (t >= d) ? sh[t - d] : 0;
        __syncthreads();
        sh[t] += x;
        __syncthreads();
    }
    bbase[t] = sh[t] - v;
    if (t == 255) bbase[256] = NEDGES;
}

// scatter packed (dlow<<16 | src) into reserved per-(wg,bucket) segments
__global__ __launch_bounds__(256) void k_bscatter(const int* __restrict__ src,
                                                  const int* __restrict__ dst,
                                                  const int* __restrict__ bbase,
                                                  const int* __restrict__ wgoff,
                                                  unsigned* __restrict__ tmp) {
    __shared__ int cur[256];
    __shared__ int base[256];
    int t = threadIdx.x, w = blockIdx.x;
    cur[t] = 0;
    base[t] = bbase[t] + wgoff[w * 256 + t];
    __syncthreads();
    const int* dp = dst + w * 4096;
    const int* sp = src + w * 4096;
    for (int k = 0; k < 16; ++k) {
        int d = dp[k * 256 + t], s = sp[k * 256 + t];
        int b = d >> 8;
        int lr = atomicAdd(&cur[b], 1);
        tmp[base[b] + lr] = ((unsigned)(d & 255) << 16) | (unsigned)s;
    }
}

// one wg per bucket: build node-level CSR in LDS, write out coalesced.
__global__ __launch_bounds__(256) void k_bcsr(const unsigned* __restrict__ tmp,
                                              const int* __restrict__ bbase,
                                              int* __restrict__ offs,
                                              float* __restrict__ dinv,
                                              unsigned short* __restrict__ csr16) {
    __shared__ unsigned pairs[BCAP];
    __shared__ unsigned short image[BCAP];
    __shared__ int cnt[256], cur[256], sh[256];
    int t = threadIdx.x, b = blockIdx.x;
    int base = bbase[b], n = bbase[b + 1] - base;
    for (int i = t; i < n; i += 256) pairs[i] = tmp[base + i];
    cnt[t] = 0;
    __syncthreads();
    for (int i = t; i < n; i += 256) atomicAdd(&cnt[pairs[i] >> 16], 1);
    __syncthreads();
    int c = cnt[t];
    sh[t] = c;
    __syncthreads();
    for (int d = 1; d < 256; d <<= 1) {
        int x = (t >= d) ? sh[t - d] : 0;
        __syncthreads();
        sh[t] += x;
        __syncthreads();
    }
    int excl = sh[t] - c;
    cur[t] = excl;
    offs[b * 256 + t] = base + excl;
    dinv[b * 256 + t] = rsqrtf((float)(c + 1));
    if (b == 255 && t == 255) offs[65536] = NEDGES;
    __syncthreads();
    for (int i = t; i < n; i += 256) {
        unsigned p = pairs[i];
        int pos = atomicAdd(&cur[p >> 16], 1);
        image[pos] = (unsigned short)(p & 0xffffu);
    }
    __syncthreads();
    for (int i = t; i < n; i += 256) csr16[base + i] = image[i];
}

// ---------------------------------------------------------- adjacency powers
// Ab[i][n][j] = bf16((A^(i+1))[n][j]), row-major — MFMA A-operand source
__global__ __launch_bounds__(256) void k_adjpow(const float* __restrict__ A,
                                                unsigned short* __restrict__ Ab) {
    __shared__ float As[4096];
    __shared__ float Bs[4096];
    int t = threadIdx.x;
    for (int q = 0; q < 16; ++q) As[t + 256 * q] = A[t + 256 * q];
    __syncthreads();
    for (int q = 0; q < 16; ++q) {
        int idx = t + 256 * q;
        int n = idx >> 6, j = idx & 63;
        Ab[idx] = bfr(As[idx]);
        float acc = 0.f;
        for (int k = 0; k < 64; ++k) acc += As[n * 64 + k] * As[k * 64 + j];
        Bs[idx] = acc;
        Ab[4096 + idx] = bfr(acc);
    }
    __syncthreads();
    for (int q = 0; q < 16; ++q) {
        int idx = t + 256 * q;
        int n = idx >> 6, j = idx & 63;
        float acc = 0.f;
        for (int k = 0; k < 64; ++k) acc += Bs[n * 64 + k] * As[k * 64 + j];
        Ab[8192 + idx] = bfr(acc);
    }
}

// ------------------------------------------------------------- conversions
__global__ void k_cvt_x(const float4* __restrict__ x, ushort4* __restrict__ o) {
    int i = blockIdx.x * 256 + threadIdx.x;
    float4 v = x[i];
    ushort4 u;
    u.x = bfr(v.x); u.y = bfr(v.y); u.z = bfr(v.z); u.w = bfr(v.w);
    o[i] = u;
}

// Wt[m][n][k] (bf16, transposed)
__global__ __launch_bounds__(256) void k_cvt_w(const float* __restrict__ gcnW,
                                               const float* __restrict__ W1,
                                               const float* __restrict__ W2,
                                               unsigned short* __restrict__ Wt) {
    int b = blockIdx.x, t = threadIdx.x;
    int m = b >> 6;
    int idx = (b & 63) * 256 + t;
    const float* src;
    int N = 128;
    if (m < 12)       src = gcnW + m * 16384;
    else if (m == 12) src = W1;
    else { src = W2; N = 64; if (idx >= 8192) return; }
    int n = idx >> 7, k = idx & 127;
    Wt[m * 16384 + idx] = bfr(src[k * N + n]);
}

// ---------------------------------------------------------------- meta mix (MFMA)
#define CPAD 258
__global__ __launch_bounds__(256) void k_mixX(const unsigned short* __restrict__ X,
                                              const unsigned short* __restrict__ Ab,
                                              unsigned short* __restrict__ Xm) {
    __shared__ unsigned short Us[64 * CPAD];
    int t = threadIdx.x;
    long c0 = (long)blockIdx.x * 256;
    int wave = t >> 6, lane = t & 63;
    int l16 = lane & 15, kg = lane >> 4;
    {
        int col = (t & 63) * 4;
        for (int q = 0; q < 16; ++q) {
            int row = q * 4 + (t >> 6);
            *(ushort4*)&Us[row * CPAD + col] =
                *(const ushort4*)(X + (long)row * COLS + c0 + col);
        }
    }
    bf8_t a[3][2];
#pragma unroll
    for (int i = 0; i < 3; ++i)
#pragma unroll
        for (int kb = 0; kb < 2; ++kb)
            a[i][kb] = *(const bf8_t*)(Ab + i * 4096 + (wave * 16 + l16) * 64 +
                                       kb * 32 + kg * 8);
    __syncthreads();
    f4_t zero4 = {0.f, 0.f, 0.f, 0.f};
    for (int cs = 0; cs < 16; ++cs) {
        int cc = cs * 16 + l16;
        bf8_t b0, b1;
#pragma unroll
        for (int jj = 0; jj < 8; ++jj) {
            b0[jj] = (short)Us[(kg * 8 + jj) * CPAD + cc];
            b1[jj] = (short)Us[(32 + kg * 8 + jj) * CPAD + cc];
        }
        f4_t acc0 = zero4, acc1 = zero4, acc2 = zero4;
        acc0 = __builtin_amdgcn_mfma_f32_16x16x32_bf16(a[0][0], b0, acc0, 0, 0, 0);
        acc1 = __builtin_amdgcn_mfma_f32_16x16x32_bf16(a[1][0], b0, acc1, 0, 0, 0);
        acc2 = __builtin_amdgcn_mfma_f32_16x16x32_bf16(a[2][0], b0, acc2, 0, 0, 0);
        acc0 = __builtin_amdgcn_mfma_f32_16x16x32_bf16(a[0][1], b1, acc0, 0, 0, 0);
        acc1 = __builtin_amdgcn_mfma_f32_16x16x32_bf16(a[1][1], b1, acc1, 0, 0, 0);
        acc2 = __builtin_amdgcn_mfma_f32_16x16x32_bf16(a[2][1], b1, acc2, 0, 0, 0);
#pragma unroll
        for (int r = 0; r < 4; ++r) {
            long n = wave * 16 + kg * 4 + r;
            long o = n * COLS + c0 + cc;
            Xm[o]                        = bfr(acc0[r]);
            Xm[(long)NNODES * D + o]     = bfr(acc1[r]);
            Xm[(long)2 * NNODES * D + o] = bfr(acc2[r]);
        }
    }
}

// ----------------------------------------------------------------- fused GEMM
__global__ __launch_bounds__(256) void k_mgemm(const unsigned short* __restrict__ X0,
                                               const unsigned short* __restrict__ Xm,
                                               const unsigned short* __restrict__ Wt4,
                                               unsigned short* __restrict__ Y) {
    int wave = threadIdx.x >> 6, lane = threadIdx.x & 63;
    int l16 = lane & 15, kg = lane >> 4;
    long row0 = (long)blockIdx.x * 128 + wave * 32;

    f4_t acc[2][8];
    f4_t zero4 = {0.f, 0.f, 0.f, 0.f};
#pragma unroll
    for (int mt = 0; mt < 2; ++mt)
#pragma unroll
        for (int nt = 0; nt < 8; ++nt) acc[mt][nt] = zero4;

#pragma unroll
    for (int z = 0; z < 4; ++z) {
        const unsigned short* Xz = (z == 0) ? X0 : Xm + (long)(z - 1) * NNODES * D;
        const unsigned short* xp = Xz + row0 * 128 + kg * 8;
        const unsigned short* wp = Wt4 + z * 16384 + (long)l16 * 128 + kg * 8;
#pragma unroll
        for (int kb = 0; kb < 4; ++kb) {
            bf8_t a0 = *(const bf8_t*)(xp + (long)l16 * 128 + kb * 32);
            bf8_t a1 = *(const bf8_t*)(xp + (long)(l16 + 16) * 128 + kb * 32);
#pragma unroll
            for (int nt = 0; nt < 8; ++nt) {
                bf8_t b = *(const bf8_t*)(wp + nt * 16 * 128 + kb * 32);
                acc[0][nt] = __builtin_amdgcn_mfma_f32_16x16x32_bf16(a0, b, acc[0][nt], 0, 0, 0);
                acc[1][nt] = __builtin_amdgcn_mfma_f32_16x16x32_bf16(a1, b, acc[1][nt], 0, 0, 0);
            }
        }
    }
#pragma unroll
    for (int mt = 0; mt < 2; ++mt)
#pragma unroll
        for (int nt = 0; nt < 8; ++nt)
#pragma unroll
            for (int r = 0; r < 4; ++r) {
                long row = row0 + mt * 16 + kg * 4 + r;
                int col = nt * 16 + l16;
                Y[row * 128 + col] = bfr(acc[mt][nt][r]);
            }
}

// ----------------------------------------------------------------- MFMA GEMM (MLP)
template <int NT, bool RELU, bool OUT_BF16>
__global__ __launch_bounds__(256) void k_mfma(const unsigned short* __restrict__ X,
                                              const unsigned short* __restrict__ Wt,
                                              const float* __restrict__ bias,
                                              void* __restrict__ Cout) {
    int wave = threadIdx.x >> 6, lane = threadIdx.x & 63;
    int l16 = lane & 15, kg = lane >> 4;
    long row0 = (long)blockIdx.x * 128 + wave * 32;
    const int NCOL = NT * 16;

    bf8_t a[2][4];
    const unsigned short* xp = X + row0 * 128 + kg * 8;
#pragma unroll
    for (int kb = 0; kb < 4; ++kb) {
        a[0][kb] = *(const bf8_t*)(xp + (long)l16 * 128 + kb * 32);
        a[1][kb] = *(const bf8_t*)(xp + (long)(l16 + 16) * 128 + kb * 32);
    }
    f4_t acc[2][NT];
    f4_t zero4 = {0.f, 0.f, 0.f, 0.f};
#pragma unroll
    for (int mt = 0; mt < 2; ++mt)
#pragma unroll
        for (int nt = 0; nt < NT; ++nt) acc[mt][nt] = zero4;

    const unsigned short* wp = Wt + (long)l16 * 128 + kg * 8;
#pragma unroll
    for (int kb = 0; kb < 4; ++kb)
#pragma unroll
        for (int nt = 0; nt < NT; ++nt) {
            bf8_t b = *(const bf8_t*)(wp + nt * 16 * 128 + kb * 32);
            acc[0][nt] = __builtin_amdgcn_mfma_f32_16x16x32_bf16(a[0][kb], b, acc[0][nt], 0, 0, 0);
            acc[1][nt] = __builtin_amdgcn_mfma_f32_16x16x32_bf16(a[1][kb], b, acc[1][nt], 0, 0, 0);
        }
#pragma unroll
    for (int mt = 0; mt < 2; ++mt)
#pragma unroll
        for (int nt = 0; nt < NT; ++nt)
#pragma unroll
            for (int r = 0; r < 4; ++r) {
                long row = row0 + mt * 16 + kg * 4 + r;
                int col = nt * 16 + l16;
                float v = acc[mt][nt][r] + bias[col];
                if (RELU) v = fmaxf(v, 0.f);
                long o = row * NCOL + col;
                if (OUT_BF16) ((unsigned short*)Cout)[o] = bfr(v);
                else          ((float*)Cout)[o] = v;
            }
}

// -------------------------------------------------------------- propagation
__global__ __launch_bounds__(256) void k_prop(const unsigned short* __restrict__ Y,
                                              const int* __restrict__ offs,
                                              const unsigned short* __restrict__ csr,
                                              const float* __restrict__ dinv,
                                              const float* __restrict__ bias4,
                                              unsigned short* __restrict__ Xout) {
    int wid = threadIdx.x >> 6;
    int lane = threadIdx.x & 63;
    int q = lane >> 4;
    int l = lane & 15;
    int v = blockIdx.x * 4 + wid;
    const uint4* Y4 = (const uint4*)Y;
    int e0 = offs[v], e1 = offs[v + 1];
    float acc[8];
#pragma unroll
    for (int k = 0; k < 8; ++k) acc[k] = 0.f;

    int e = e0 + q;
    for (; e + 4 < e1; e += 8) {
        int u0 = csr[e], u1 = csr[e + 4];
        float d0 = dinv[u0], d1 = dinv[u1];
        uint4 y0 = Y4[(long)u0 * 16 + l];
        uint4 y1 = Y4[(long)u1 * 16 + l];
        float f0[8], f1[8];
        unpack8(y0, f0);
        unpack8(y1, f1);
#pragma unroll
        for (int k = 0; k < 8; ++k) acc[k] += d0 * f0[k] + d1 * f1[k];
    }
    if (e < e1) {
        int u = csr[e];
        float du = dinv[u];
        uint4 y = Y4[(long)u * 16 + l];
        float f[8];
        unpack8(y, f);
#pragma unroll
        for (int k = 0; k < 8; ++k) acc[k] += du * f[k];
    }
#pragma unroll
    for (int k = 0; k < 8; ++k) {
        acc[k] += __shfl_xor(acc[k], 32, 64);
        acc[k] += __shfl_xor(acc[k], 16, 64);
    }
    if (q == 0) {
        float dv = dinv[v];
        float dvv = dv * dv;
        uint4 s = Y4[(long)v * 16 + l];
        float sf[8];
        unpack8(s, sf);
        float bs[8];
#pragma unroll
        for (int k = 0; k < 8; ++k) bs[k] = 0.f;
#pragma unroll
        for (int p = 0; p < 4; ++p) {
            float4 blo = *(const float4*)(bias4 + p * 128 + l * 8);
            float4 bhi = *(const float4*)(bias4 + p * 128 + l * 8 + 4);
            bs[0] += blo.x; bs[1] += blo.y; bs[2] += blo.z; bs[3] += blo.w;
            bs[4] += bhi.x; bs[5] += bhi.y; bs[6] += bhi.z; bs[7] += bhi.w;
        }
        unsigned r[8];
#pragma unroll
        for (int k = 0; k < 8; ++k)
            r[k] = bfr(fmaxf(dv * acc[k] + dvv * sf[k] + bs[k], 0.f));
        uint4 pk;
        pk.x = (r[1] << 16) | r[0];
        pk.y = (r[3] << 16) | r[2];
        pk.z = (r[5] << 16) | r[4];
        pk.w = (r[7] << 16) | r[6];
        ((uint4*)Xout)[(long)v * 16 + l] = pk;
    }
}

// ------------------------------------------------------------------ launch
extern "C" void kernel_launch(void* const* d_in, const int* in_sizes, int n_in,
                              void* d_out, int out_size, void* d_ws, size_t ws_size,
                              hipStream_t stream) {
    const float* x      = (const float*)d_in[0];
    const int*   subadj = (const int*)d_in[1];
    const float* adj    = (const float*)d_in[2];
    const float* gcn_W  = (const float*)d_in[3];
    const float* gcn_b  = (const float*)d_in[4];
    const float* lin_W1 = (const float*)d_in[5];
    const float* lin_b1 = (const float*)d_in[6];
    const float* lin_W2 = (const float*)d_in[7];
    const float* lin_b2 = (const float*)d_in[8];
    float* out = (float*)d_out;

    const int* e_src = subadj;
    const int* e_dst = subadj + NEDGES;

    char* w = (char*)d_ws;
    int*      bcnt  = (int*)w;      w += (size_t)256 * 4;
    int*      bbase = (int*)w;      w += (size_t)260 * 4;
    int*      wgoff = (int*)w;      w += (size_t)65536 * 4;
    int*      offs  = (int*)w;      w += (size_t)65540 * 4;
    float*    dinv  = (float*)w;    w += (size_t)65536 * 4;
    unsigned* tmp   = (unsigned*)w; w += (size_t)NEDGES * 4;
    unsigned short* csr16 = (unsigned short*)w; w += (size_t)NEDGES * 2;
    unsigned short* Ab  = (unsigned short*)w; w += (size_t)3 * 4096 * 2;
    unsigned short* Xbf = (unsigned short*)w; w += (size_t)NNODES * D * 2;
    unsigned short* Xm  = (unsigned short*)w; w += (size_t)3 * NNODES * D * 2;
    unsigned short* Ybf = (unsigned short*)w; w += (size_t)NNODES * D * 2;
    unsigned short* Wt  = (unsigned short*)w; w += (size_t)14 * 16384 * 2;
    unsigned short* Hbf = (unsigned short*)w; w += (size_t)NNODES * D * 2;

    k_zero256<<<1, 256, 0, stream>>>(bcnt);
    k_bhist<<<256, 256, 0, stream>>>(e_dst, bcnt, wgoff);
    k_bscan<<<1, 256, 0, stream>>>(bcnt, bbase);
    k_bscatter<<<256, 256, 0, stream>>>(e_src, e_dst, bbase, wgoff, tmp);
    k_bcsr<<<256, 256, 0, stream>>>(tmp, bbase, offs, dinv, csr16);
    k_adjpow<<<1, 256, 0, stream>>>(adj, Ab);
    k_cvt_x<<<NNODES * D / 4 / 256, 256, 0, stream>>>((const float4*)x, (ushort4*)Xbf);
    k_cvt_w<<<896, 256, 0, stream>>>(gcn_W, lin_W1, lin_W2, Wt);

    for (int li = 0; li < 3; ++li) {
        k_mixX<<<COLS / 256, 256, 0, stream>>>(Xbf, Ab, Xm);
        k_mgemm<<<NNODES / 128, 256, 0, stream>>>(Xbf, Xm, Wt + (size_t)li * 4 * 16384, Ybf);
        k_prop<<<NNODES / 4, 256, 0, stream>>>(Ybf, offs, csr16, dinv,
                                               gcn_b + (size_t)li * 512, Xbf);
    }
    k_mfma<8, true, true><<<NNODES / 128, 256, 0, stream>>>(
        Xbf, Wt + (size_t)12 * 16384, lin_b1, Hbf);
    k_mfma<4, false, false><<<NNODES / 128, 256, 0, stream>>>(
        Hbf, Wt + (size_t)13 * 16384, lin_b2, out);
}